// Round 14
// baseline (626.776 us; speedup 1.0000x reference)
//
#include <hip/hip_runtime.h>
#include <hip/hip_bf16.h>
#include <cstdint>
#include <cstddef>

typedef __attribute__((ext_vector_type(4))) int   i32x4;
typedef __attribute__((ext_vector_type(4))) float f32x4;

#define DEVI static __device__ __forceinline__

DEVI void gload_lds16(const void* g, void* l) {
    __builtin_amdgcn_global_load_lds((const __attribute__((address_space(1))) void*)g,
                                     (__attribute__((address_space(3))) void*)l, 16, 0, 0);
}

#define BARR() __builtin_amdgcn_s_barrier()
#define LGKM0() do { asm volatile("s_waitcnt lgkmcnt(0)" ::: "memory"); \
                     __builtin_amdgcn_sched_barrier(0); } while (0)
#define SCHED0() __builtin_amdgcn_sched_barrier(0)
#define VMW(n) asm volatile("s_waitcnt vmcnt(" #n ")" ::: "memory")
#define SP(x) __builtin_amdgcn_s_setprio(x)

DEVI int q8(float v, float s) {
    int q = __float2int_rn(v * s);
    return q < -127 ? -127 : (q > 127 ? 127 : q);
}

// ---------------------------------------------------------------------------
// Prep: quantize x identity half AND write the output identity half.
// ---------------------------------------------------------------------------
__global__ __launch_bounds__(256)
void prep_x_kernel(const float* __restrict__ x, char* __restrict__ xq,
                   float* __restrict__ out) {
    int g = blockIdx.x * 256 + threadIdx.x;     // over B*32
    int row = g >> 5, c8 = (g & 31) * 8;
    const float4 v0 = *(const float4*)(x + (size_t)row * 512 + c8);
    const float4 v1 = *(const float4*)(x + (size_t)row * 512 + c8 + 4);
    *(float4*)(out + (size_t)row * 512 + c8)     = v0;   // identity copy
    *(float4*)(out + (size_t)row * 512 + c8 + 4) = v1;
    unsigned p0 = (q8(v0.x,20.f)&255) | ((q8(v0.y,20.f)&255)<<8) |
                  ((q8(v0.z,20.f)&255)<<16) | ((unsigned)(q8(v0.w,20.f)&255)<<24);
    unsigned p1 = (q8(v1.x,20.f)&255) | ((q8(v1.y,20.f)&255)<<8) |
                  ((q8(v1.z,20.f)&255)<<16) | ((unsigned)(q8(v1.w,20.f)&255)<<24);
    *(int2*)(xq + (size_t)row * 256 + c8) = make_int2((int)p0, (int)p1);
}

// ---------------------------------------------------------------------------
// Merged weight prep: transpose+quant W1,W2,W3; permuted transpose+quant W4.
// ---------------------------------------------------------------------------
__global__ __launch_bounds__(256)
void prep_w_kernel(const float* __restrict__ W1, const float* __restrict__ W2,
                   const float* __restrict__ W3, const float* __restrict__ W4,
                   const float* __restrict__ b4, char* __restrict__ W1q,
                   char* __restrict__ W2q, char* __restrict__ W3q,
                   char* __restrict__ W4q, float* __restrict__ b4p) {
    int idx = blockIdx.x * 256 + threadIdx.x;
    if (idx < 262144) {                         // W1: N=1024, K=256
        int n = idx >> 8, k = idx & 255;
        W1q[idx] = (char)q8(W1[(size_t)k * 1024 + n], 2032.f);
    } else if (idx < 262144 + 1048576) {        // W2: N=K=1024
        int j = idx - 262144;
        int n = j >> 10, k = j & 1023;
        W2q[j] = (char)q8(W2[(size_t)k * 1024 + n], 4064.f);
    } else if (idx < 262144 + 2097152) {        // W3
        int j = idx - 262144 - 1048576;
        int n = j >> 10, k = j & 1023;
        W3q[j] = (char)q8(W3[(size_t)k * 1024 + n], 4064.f);
    } else {                                    // W4 permuted: vt in [0,512)
        int j = idx - 262144 - 2097152;
        int vt = j >> 10, k = j & 1023;
        int bn = vt >> 8, v = vt & 255;
        int v16 = v >> 4, c = v & 15;
        int tcol = bn * 128 + (v16 >> 1) * 16 + c;
        int col = (v16 & 1) ? 256 + tcol : tcol;
        W4q[j] = (char)q8(W4[(size_t)k * 512 + col], 4064.f);
        if (k == 0) b4p[vt] = b4[col];
    }
}

// ---------------------------------------------------------------------------
// Persistent 256x256 i8 GEMM, BK=128. A staged into 2x32KB LDS buffers
// (swizzled, gload_lds); B loaded GLOBAL->REGISTER (L1/L2-resident panel),
// double-buffered one K-tile ahead (plain loads: compiler-tracked waits).
// Per phase t: GLBB(t+1) 8 loads | RDSA 16 ds_read_b128 | MMH(0) |
// LGKM0+BARR#1 (A reads done block-wide) | STAGE_A(t+2) into buf t&1
// (race-free after BARR#1) | MMH(1) | VMW(12)+BARR#2 (12 newer vmem ops =
// own GLBB 8 + STAGE 4, so stage(t+1) retired block-wide). Prologue
// full-drain VMW(0) (R8 lesson). LDS reads/phase cut 192KB->128KB (B gone).
// MODE 0: dequant+bias+relu+requant -> i8. MODE 2: fused coupling epilogue.
// ---------------------------------------------------------------------------
#define RDSA(p) do { \
    const char* _a = lds + (p) * 32768; \
    _Pragma("unroll") \
    for (int mt = 0; mt < 8; ++mt) aF[mt][0] = *(const i32x4*)(_a + aRow + mt * 2048 + ck0); \
    _Pragma("unroll") \
    for (int mt = 0; mt < 8; ++mt) aF[mt][1] = *(const i32x4*)(_a + aRow + mt * 2048 + ck1); \
} while (0)

#define GLBB(DST, t) do { \
    const int _kb = (((t) < GT ? (t) : GT - 1) & (NI2 - 1)) * 128; \
    _Pragma("unroll") \
    for (int nt = 0; nt < 4; ++nt) { \
        DST[nt][0] = *(const i32x4*)(bBase + (size_t)(nt * 16) * K + _kb + lq * 16); \
        DST[nt][1] = *(const i32x4*)(bBase + (size_t)(nt * 16) * K + _kb + 64 + lq * 16); \
    } \
} while (0)

#define MMH(S, BSET) do { \
    SP(1); \
    _Pragma("unroll") \
    for (int mt = 0; mt < 8; ++mt) \
        _Pragma("unroll") \
        for (int nt = 0; nt < 4; ++nt) \
            acc[mt][nt] = __builtin_amdgcn_mfma_i32_16x16x64_i8(BSET[nt][S], aF[mt][S], acc[mt][nt], 0, 0, 0); \
    SP(0); \
} while (0)

// one K-128 phase: prefetch B(t+1), read A(t) frags, 2 MFMA halves,
// stage A(t+2) between the barriers.
#define PHASE(BC, BN, t) do { \
    GLBB(BN, (t) + 1); \
    SCHED0(); \
    RDSA((t) & 1); \
    MMH(0, BC); \
    LGKM0(); \
    BARR(); \
    SCHED0(); \
    STAGE_A((t) + 2); \
    MMH(1, BC); \
    VMW(12); SCHED0(); \
    BARR(); \
} while (0)

template<int MODE, int NI2, int TPB>
__global__ __launch_bounds__(512)
void gemmQ_kernel(const char* __restrict__ A, const char* __restrict__ Bt,
                  const float* __restrict__ bias, void* __restrict__ Cp,
                  const float* __restrict__ x, float* __restrict__ part,
                  int N, int K, int gx, float invS) {
    constexpr int GT = NI2 * TPB;
    __shared__ __align__(16) char lds[65536];  // 2 x 32KB (A only)

    const int tid = threadIdx.x;
    const int bid = blockIdx.x;                // grid = 256, persistent
    const int xcd = bid & 7, bidx = bid >> 3;
    const int bn = bidx % gx;                  // fixed per block (B panel L2-hot)
    const int mgrp = bidx / gx;
    const int colBase = bn * 256;
    const int l  = tid & 63;
    const int w  = tid >> 6;
    const int wm = w >> 2, wn = w & 3;
    const int lr = l & 15, lq = l >> 4;
    const int gsw = (lr >> 1) & 7;

    const int aRow = (wm * 128 + lr) * 128;    // + mt*2048 (128 B rows)
    const int ck0 = ((lq ^ gsw) & 7) * 16;
    const int ck1 = (((4 | lq) ^ gsw) & 7) * 16;
    const char* bBase = Bt + (size_t)(colBase + wn * 64 + lr) * K;

    auto rowBaseOf = [&](int tt) { return (xcd * 32 + mgrp * TPB + tt) * 256; };

    auto STAGE_A = [&](int gd) {               // A 32KB of K-tile gd (4 issues)
        const int gs = gd < GT ? gd : GT - 1;  // tail clamp (safe: after BARR#1)
        const int kb = (gs & (NI2 - 1)) * 128;
        const int arb = rowBaseOf(gs / NI2);
        char* da = lds + (gd & 1) * 32768;
#pragma unroll
        for (int u = 0; u < 4; ++u) {
            int row = u * 64 + (tid >> 3);
            int c = (tid & 7) ^ ((row >> 1) & 7);
            gload_lds16(A + (size_t)(arb + row) * K + kb + c * 16, da + u * 8192 + tid * 16);
        }
    };

    i32x4 acc[8][4];
    const i32x4 zero = {0, 0, 0, 0};
#pragma unroll
    for (int m = 0; m < 8; ++m)
#pragma unroll
        for (int n = 0; n < 4; ++n) acc[m][n] = zero;
    i32x4 aF[8][2], bFX[4][2], bFY[4][2];

    auto epi = [&](int tt) {
        float4 bv[4];
#pragma unroll
        for (int n = 0; n < 4; ++n)
            bv[n] = *(const float4*)(bias + colBase + wn * 64 + n * 16 + lq * 4);
        const int rowBase = rowBaseOf(tt);
        const int row0 = rowBase + wm * 128;
        if (MODE == 0) {
            char* C = (char*)Cp;
#pragma unroll
            for (int m = 0; m < 8; ++m) {
                const int row = row0 + m * 16 + lr;
#pragma unroll
                for (int n = 0; n < 4; ++n) {
                    unsigned pack = 0;
#pragma unroll
                    for (int r = 0; r < 4; ++r) {
                        float v = (float)acc[m][n][r] * invS + ((const float*)&bv[n])[r];
                        v = fmaxf(v, 0.f);
                        int q = (int)(fminf(v, 7.9f) * 16.f + 0.5f);
                        pack |= (unsigned)q << (8 * r);
                    }
                    *(int*)(C + (size_t)row * N + colBase + wn * 64 + n * 16 + lq * 4) = (int)pack;
                }
            }
        } else {
            const int B = 65536;
            float* out = (float*)Cp;
#pragma unroll
            for (int m = 0; m < 8; ++m) {
                const int row = row0 + m * 16 + lr;
                float lsum = 0.f;
#pragma unroll
                for (int p = 0; p < 2; ++p) {
                    const int tcol = bn * 128 + wn * 32 + p * 16 + lq * 4;
                    const float4 xt = *(const float4*)(x + (size_t)row * 512 + 256 + tcol);
                    float4 ov;
#pragma unroll
                    for (int r = 0; r < 4; ++r) {
                        float sh = (float)acc[m][2 * p][r]     * invS + ((const float*)&bv[2 * p])[r];
                        float u  = (float)acc[m][2 * p + 1][r] * invS + ((const float*)&bv[2 * p + 1])[r];
                        float s  = 1.f / (1.f + __expf(-(u + 2.f))) + 0.001f;
                        ((float*)&ov)[r] = ((const float*)&xt)[r] * s + sh;
                        lsum += __logf(s);
                    }
                    *(float4*)(out + (size_t)row * 512 + 256 + tcol) = ov;
                }
                lsum += __shfl_xor(lsum, 16);
                lsum += __shfl_xor(lsum, 32);
                if (lq == 0) part[(size_t)(bn * 4 + wn) * B + row] = lsum;
            }
        }
#pragma unroll
        for (int m = 0; m < 8; ++m)
#pragma unroll
            for (int n = 0; n < 4; ++n) acc[m][n] = zero;
    };

    // ---- prologue: stage A tiles 0,1; prefetch B(0); full drain ----
    STAGE_A(0); STAGE_A(1);
    GLBB(bFX, 0);
    VMW(0);
    BARR();

#pragma unroll 1
    for (int t = 0; t < GT; t += 2) {
        PHASE(bFX, bFY, t);
        PHASE(bFY, bFX, t + 1);
        if (((t + 2) & (NI2 - 1)) == 0) epi((t + 2) / NI2 - 1);
    }
}

__global__ __launch_bounds__(256)
void lad_reduce_kernel(const float* __restrict__ part, float* __restrict__ lad) {
    const int B = 65536;
    int rIdx = blockIdx.x * 256 + threadIdx.x;
    float s = 0.f;
#pragma unroll
    for (int j = 0; j < 8; ++j) s += part[(size_t)j * B + rIdx];
    lad[rIdx] = s;
}

// ---------------------------------------------------------------------------
extern "C" void kernel_launch(void* const* d_in, const int* in_sizes, int n_in,
                              void* d_out, int out_size, void* d_ws, size_t ws_size,
                              hipStream_t stream) {
    const int B = 65536, D_ID = 256, H = 1024, NP = 512;

    const float* x  = (const float*)d_in[0];
    const float* W1 = (const float*)d_in[1];
    const float* b1 = (const float*)d_in[2];
    const float* W2 = (const float*)d_in[3];
    const float* b2 = (const float*)d_in[4];
    const float* W3 = (const float*)d_in[5];
    const float* b3 = (const float*)d_in[6];
    const float* W4 = (const float*)d_in[7];
    const float* b4 = (const float*)d_in[8];

    float* out = (float*)d_out;
    float* lad = out + (size_t)B * 512;

    const float invS1  = 1.f / (20.f * 2032.f);
    const float invS23 = 1.f / (16.f * 4064.f);

    char* ws = (char*)d_ws;
    const size_t hbytes = (size_t)B * H;                       // 64 MiB (i8)
    char*  hA   = ws;
    char*  hB   = ws + hbytes;
    char*  xq   = ws + hbytes;                                 // alias hB (dead before L2)
    float* part = (float*)(ws + hbytes);                       // alias hB (dead after L3)
    char*  W1q  = ws + 2 * hbytes;
    char*  W2q  = W1q + (size_t)H * D_ID;
    char*  W3q  = W2q + (size_t)H * H;
    char*  W4q  = W3q + (size_t)H * H;
    float* b4p  = (float*)(W4q + (size_t)NP * H);

    dim3 blk(256), blk8(512);
    prep_x_kernel<<<dim3(B * 32 / 256), blk, 0, stream>>>(x, xq, out);
    prep_w_kernel<<<dim3(11264), blk, 0, stream>>>(W1, W2, W3, W4, b4,
                                                   W1q, W2q, W3q, W4q, b4p);

    // all GEMMs persistent: grid 256 = 1 block/CU, 512 threads
    gemmQ_kernel<0, 2, 4><<<dim3(256), blk8, 0, stream>>>(xq, W1q, b1, hA, nullptr, nullptr, H, D_ID, 4, invS1);
    gemmQ_kernel<0, 8, 4><<<dim3(256), blk8, 0, stream>>>(hA, W2q, b2, hB, nullptr, nullptr, H, H, 4, invS23);
    gemmQ_kernel<0, 8, 4><<<dim3(256), blk8, 0, stream>>>(hB, W3q, b3, hA, nullptr, nullptr, H, H, 4, invS23);
    gemmQ_kernel<2, 8, 2><<<dim3(256), blk8, 0, stream>>>(hA, W4q, b4p, out, x, part, NP, H, 2, invS23);

    lad_reduce_kernel<<<dim3(B / 256), blk, 0, stream>>>(part, lad);
}

// Round 15
// 335.794 us; speedup vs baseline: 1.8666x; 1.8666x over previous
//
#include <hip/hip_runtime.h>
#include <hip/hip_bf16.h>
#include <cstdint>
#include <cstddef>

typedef __attribute__((ext_vector_type(4))) int   i32x4;
typedef __attribute__((ext_vector_type(4))) float f32x4;

#define DEVI static __device__ __forceinline__

DEVI void gload_lds16(const void* g, void* l) {
    __builtin_amdgcn_global_load_lds((const __attribute__((address_space(1))) void*)g,
                                     (__attribute__((address_space(3))) void*)l, 16, 0, 0);
}

#define BARR() __builtin_amdgcn_s_barrier()
#define LGKM0() do { asm volatile("s_waitcnt lgkmcnt(0)" ::: "memory"); \
                     __builtin_amdgcn_sched_barrier(0); } while (0)
#define SCHED0() __builtin_amdgcn_sched_barrier(0)
#define VMW(n) asm volatile("s_waitcnt vmcnt(" #n ")" ::: "memory")
#define SP(x) __builtin_amdgcn_s_setprio(x)

DEVI int q8(float v, float s) {
    int q = __float2int_rn(v * s);
    return q < -127 ? -127 : (q > 127 ? 127 : q);
}

// ---------------------------------------------------------------------------
// Prep: quantize x identity half AND write the output identity half.
// ---------------------------------------------------------------------------
__global__ __launch_bounds__(256)
void prep_x_kernel(const float* __restrict__ x, char* __restrict__ xq,
                   float* __restrict__ out) {
    int g = blockIdx.x * 256 + threadIdx.x;     // over B*32
    int row = g >> 5, c8 = (g & 31) * 8;
    const float4 v0 = *(const float4*)(x + (size_t)row * 512 + c8);
    const float4 v1 = *(const float4*)(x + (size_t)row * 512 + c8 + 4);
    *(float4*)(out + (size_t)row * 512 + c8)     = v0;   // identity copy
    *(float4*)(out + (size_t)row * 512 + c8 + 4) = v1;
    unsigned p0 = (q8(v0.x,20.f)&255) | ((q8(v0.y,20.f)&255)<<8) |
                  ((q8(v0.z,20.f)&255)<<16) | ((unsigned)(q8(v0.w,20.f)&255)<<24);
    unsigned p1 = (q8(v1.x,20.f)&255) | ((q8(v1.y,20.f)&255)<<8) |
                  ((q8(v1.z,20.f)&255)<<16) | ((unsigned)(q8(v1.w,20.f)&255)<<24);
    *(int2*)(xq + (size_t)row * 256 + c8) = make_int2((int)p0, (int)p1);
}

// ---------------------------------------------------------------------------
// Merged weight prep: transpose+quant W1,W2,W3; permuted transpose+quant W4.
// ---------------------------------------------------------------------------
__global__ __launch_bounds__(256)
void prep_w_kernel(const float* __restrict__ W1, const float* __restrict__ W2,
                   const float* __restrict__ W3, const float* __restrict__ W4,
                   const float* __restrict__ b4, char* __restrict__ W1q,
                   char* __restrict__ W2q, char* __restrict__ W3q,
                   char* __restrict__ W4q, float* __restrict__ b4p) {
    int idx = blockIdx.x * 256 + threadIdx.x;
    if (idx < 262144) {                         // W1: N=1024, K=256
        int n = idx >> 8, k = idx & 255;
        W1q[idx] = (char)q8(W1[(size_t)k * 1024 + n], 2032.f);
    } else if (idx < 262144 + 1048576) {        // W2: N=K=1024
        int j = idx - 262144;
        int n = j >> 10, k = j & 1023;
        W2q[j] = (char)q8(W2[(size_t)k * 1024 + n], 4064.f);
    } else if (idx < 262144 + 2097152) {        // W3
        int j = idx - 262144 - 1048576;
        int n = j >> 10, k = j & 1023;
        W3q[j] = (char)q8(W3[(size_t)k * 1024 + n], 4064.f);
    } else {                                    // W4 permuted: vt in [0,512)
        int j = idx - 262144 - 2097152;
        int vt = j >> 10, k = j & 1023;
        int bn = vt >> 8, v = vt & 255;
        int v16 = v >> 4, c = v & 15;
        int tcol = bn * 128 + (v16 >> 1) * 16 + c;
        int col = (v16 & 1) ? 256 + tcol : tcol;
        W4q[j] = (char)q8(W4[(size_t)k * 512 + col], 4064.f);
        if (k == 0) b4p[vt] = b4[col];
    }
}

// ---------------------------------------------------------------------------
// Persistent 256x256 i8 GEMM — byte-for-byte i8 transplant of the R6 bf16
// structure (the fastest measured bf16 donor: 145 vs R11's 166 us).
// K-tile = 64 i8 (64 B rows, same bytes as R6's 32 bf16). 4 LDS buffers x
// (A 16KB + B 16KB) = 128KB. Two phases per K-tile, ONE barrier per phase,
// register-pipelined operands (reads for phase p+1 issued in phase p):
//  PHASE0(t): RD_B(b1, t, cols2-3) | STAGE_A(t+3) | MFMA(b0 x A(t)) cols0-1
//             | LGKM0 | BARR
//  PHASE1(t): VMW(6) [retires tiles <= t+1] | RD_A(t+1) RD_B(b0, t+1)
//             | STAGE_B(t+3) | MFMA(b1 x A(t)) cols2-3 | LGKM0 | BARR
// Prologue: stage tiles 0,1,2 + VMW(0) full drain (R8 lesson). After an
// epilogue (stores in vmcnt queue) the next PHASE1 uses VMW(0).
// 8 waves 2Mx4N, wave tile 128x64, swapped-operand MFMA (C^T frags).
// MODE 0: dequant+bias+relu+requant(x16) -> i8. MODE 2: coupling epilogue.
// ---------------------------------------------------------------------------
#define RD_A(DST, g) do { \
    const char* _b = lds + ((g) & 3) * 32768; \
    _Pragma("unroll") \
    for (int m = 0; m < 8; ++m) DST[m] = *(const i32x4*)(_b + aOff + m * 1024); \
} while (0)

#define RD_B(DST, g, J0) do { \
    const char* _b = lds + ((g) & 3) * 32768 + 16384; \
    DST[0] = *(const i32x4*)(_b + bOff + (J0) * 1024); \
    DST[1] = *(const i32x4*)(_b + bOff + (J0 + 1) * 1024); \
} while (0)

#define MM2(BSET, ASET, J0) do { \
    _Pragma("unroll") \
    for (int m = 0; m < 8; ++m) { \
        acc[m][J0]     = __builtin_amdgcn_mfma_i32_16x16x64_i8(BSET[0], ASET[m], acc[m][J0], 0, 0, 0); \
        acc[m][J0 + 1] = __builtin_amdgcn_mfma_i32_16x16x64_i8(BSET[1], ASET[m], acc[m][J0 + 1], 0, 0, 0); \
    } \
} while (0)

#define PHASE0(ASET, t) do { \
    RD_B(b1, (t), 2); \
    STAGE_A((t) + 3); \
    SCHED0(); \
    SP(1); MM2(b0, ASET, 0); SP(0); \
    LGKM0(); BARR(); \
} while (0)

#define PHASE1(ASET, ANXT, t, W0) do { \
    if (W0) { VMW(0); } else { VMW(6); } \
    RD_A(ANXT, (t) + 1); \
    RD_B(b0, (t) + 1, 0); \
    STAGE_B((t) + 3); \
    SCHED0(); \
    SP(1); MM2(b1, ASET, 2); SP(0); \
    LGKM0(); BARR(); \
} while (0)

template<int MODE, int NI, int TPB>
__global__ __launch_bounds__(512)
void gemmR_kernel(const char* __restrict__ A, const char* __restrict__ Bt,
                  const float* __restrict__ bias, void* __restrict__ Cp,
                  const float* __restrict__ x, float* __restrict__ part,
                  int N, int K, int gx, float invS) {
    constexpr int GT = NI * TPB;               // K-64 tiles in block's stream
    __shared__ __align__(16) char lds[131072]; // 4 x (A 16KB + B 16KB)

    const int tid = threadIdx.x;
    const int bid = blockIdx.x;                // grid = 256, persistent
    const int xcd = bid & 7, bidx = bid >> 3;
    const int bn = bidx % gx;                  // fixed per block (B panel L2-hot)
    const int mgrp = bidx / gx;
    const int colBase = bn * 256;
    const int l  = tid & 63;
    const int w  = tid >> 6;
    const int wm = w >> 2, wn = w & 3;
    const int lr = l & 15, lq = l >> 4;
    const int qa = lq ^ ((lr >> 1) & 3);       // swizzled 16B chunk for reads

    const int aOff = (wm * 128 + lr) * 64 + qa * 16;            // + m*1024
    const int bOff = (wn * 64 + lr) * 64 + qa * 16;             // + j*1024

    // staging coords (pre-swizzled source); rows are 64 B (64 i8)
    const int sar = tid >> 2;                                   // row 0..127
    const int ca = (((tid & 3) ^ ((tid >> 3) & 3))) * 16;       // src chunk bytes

    auto rowBaseOf = [&](int tt) { return (xcd * 32 + mgrp * TPB + tt) * 256; };

    auto STAGE_A = [&](int gd) {               // A 16KB of K-tile gd (2 issues)
        const int gs = gd < GT ? gd : GT - 1;  // tail clamp
        char* dst = lds + (gd & 3) * 32768 + tid * 16;
        const char* src = A + (size_t)(rowBaseOf(gs / NI) + sar) * K
                            + (gs & (NI - 1)) * 64 + ca;
#pragma unroll
        for (int u = 0; u < 2; ++u)
            gload_lds16(src + (size_t)u * 128 * K, dst + u * 8192);
    };
    auto STAGE_B = [&](int gd) {               // B 16KB of K-tile gd (2 issues)
        const int gs = gd < GT ? gd : GT - 1;
        char* dst = lds + (gd & 3) * 32768 + 16384 + tid * 16;
        const char* src = Bt + (size_t)(colBase + sar) * K
                             + (gs & (NI - 1)) * 64 + ca;
#pragma unroll
        for (int u = 0; u < 2; ++u)
            gload_lds16(src + (size_t)u * 128 * K, dst + u * 8192);
    };

    i32x4 acc[8][4];
    const i32x4 zero = {0, 0, 0, 0};
#pragma unroll
    for (int m = 0; m < 8; ++m)
#pragma unroll
        for (int n = 0; n < 4; ++n) acc[m][n] = zero;
    i32x4 afX[8], afY[8], b0[2], b1[2];

    auto epi = [&](int tt) {
        float4 bv[4];
#pragma unroll
        for (int n = 0; n < 4; ++n)
            bv[n] = *(const float4*)(bias + colBase + wn * 64 + n * 16 + lq * 4);
        const int rowBase = rowBaseOf(tt);
        const int row0 = rowBase + wm * 128;
        if (MODE == 0) {
            char* C = (char*)Cp;
#pragma unroll
            for (int m = 0; m < 8; ++m) {
                const int row = row0 + m * 16 + lr;
#pragma unroll
                for (int n = 0; n < 4; ++n) {
                    unsigned pack = 0;
#pragma unroll
                    for (int r = 0; r < 4; ++r) {
                        float v = (float)acc[m][n][r] * invS + ((const float*)&bv[n])[r];
                        v = fmaxf(v, 0.f);
                        int q = (int)(fminf(v, 7.9f) * 16.f + 0.5f);
                        pack |= (unsigned)q << (8 * r);
                    }
                    *(int*)(C + (size_t)row * N + colBase + wn * 64 + n * 16 + lq * 4) = (int)pack;
                }
            }
        } else {
            const int B = 65536;
            float* out = (float*)Cp;
            // identity half handled by prep_x_kernel; only transform cols here
#pragma unroll
            for (int m = 0; m < 8; ++m) {
                const int row = row0 + m * 16 + lr;
                float lsum = 0.f;
#pragma unroll
                for (int p = 0; p < 2; ++p) {
                    const int tcol = bn * 128 + wn * 32 + p * 16 + lq * 4;
                    const float4 xt = *(const float4*)(x + (size_t)row * 512 + 256 + tcol);
                    float4 ov;
#pragma unroll
                    for (int r = 0; r < 4; ++r) {
                        float sh = (float)acc[m][2 * p][r]     * invS + ((const float*)&bv[2 * p])[r];
                        float u  = (float)acc[m][2 * p + 1][r] * invS + ((const float*)&bv[2 * p + 1])[r];
                        float s  = 1.f / (1.f + __expf(-(u + 2.f))) + 0.001f;
                        ((float*)&ov)[r] = ((const float*)&xt)[r] * s + sh;
                        lsum += __logf(s);
                    }
                    *(float4*)(out + (size_t)row * 512 + 256 + tcol) = ov;
                }
                lsum += __shfl_xor(lsum, 16);
                lsum += __shfl_xor(lsum, 32);
                if (lq == 0) part[(size_t)(bn * 4 + wn) * B + row] = lsum;
            }
        }
#pragma unroll
        for (int m = 0; m < 8; ++m)
#pragma unroll
            for (int n = 0; n < 4; ++n) acc[m][n] = zero;
    };

    // ---- prologue: stage tiles 0,1,2 (12 issues); full drain (R8 lesson) ----
    STAGE_A(0); STAGE_B(0); STAGE_A(1); STAGE_B(1); STAGE_A(2); STAGE_B(2);
    VMW(0);
    BARR();
    RD_A(afX, 0); RD_B(b0, 0, 0);
    LGKM0();

#pragma unroll 1
    for (int g = 0; g < GT / 2; ++g) {
        const int ta = 2 * g, tb = 2 * g + 1;
        const bool w0 = (ta > 0) && ((ta & (NI - 1)) == 0);  // drain after epilogue
        PHASE0(afX, ta);
        PHASE1(afX, afY, ta, w0);
        PHASE0(afY, tb);
        PHASE1(afY, afX, tb, false);
        if (((tb + 1) & (NI - 1)) == 0) epi((tb + 1) / NI - 1);
    }
}

__global__ __launch_bounds__(256)
void lad_reduce_kernel(const float* __restrict__ part, float* __restrict__ lad) {
    const int B = 65536;
    int rIdx = blockIdx.x * 256 + threadIdx.x;
    float s = 0.f;
#pragma unroll
    for (int j = 0; j < 8; ++j) s += part[(size_t)j * B + rIdx];
    lad[rIdx] = s;
}

// ---------------------------------------------------------------------------
extern "C" void kernel_launch(void* const* d_in, const int* in_sizes, int n_in,
                              void* d_out, int out_size, void* d_ws, size_t ws_size,
                              hipStream_t stream) {
    const int B = 65536, D_ID = 256, H = 1024, NP = 512;

    const float* x  = (const float*)d_in[0];
    const float* W1 = (const float*)d_in[1];
    const float* b1 = (const float*)d_in[2];
    const float* W2 = (const float*)d_in[3];
    const float* b2 = (const float*)d_in[4];
    const float* W3 = (const float*)d_in[5];
    const float* b3 = (const float*)d_in[6];
    const float* W4 = (const float*)d_in[7];
    const float* b4 = (const float*)d_in[8];

    float* out = (float*)d_out;
    float* lad = out + (size_t)B * 512;

    const float invS1  = 1.f / (20.f * 2032.f);
    const float invS23 = 1.f / (16.f * 4064.f);

    char* ws = (char*)d_ws;
    const size_t hbytes = (size_t)B * H;                       // 64 MiB (i8)
    char*  hA   = ws;
    char*  hB   = ws + hbytes;
    char*  xq   = ws + hbytes;                                 // alias hB (dead before L2)
    float* part = (float*)(ws + hbytes);                       // alias hB (dead after L3)
    char*  W1q  = ws + 2 * hbytes;
    char*  W2q  = W1q + (size_t)H * D_ID;
    char*  W3q  = W2q + (size_t)H * H;
    char*  W4q  = W3q + (size_t)H * H;
    float* b4p  = (float*)(W4q + (size_t)NP * H);

    dim3 blk(256), blk8(512);
    prep_x_kernel<<<dim3(B * 32 / 256), blk, 0, stream>>>(x, xq, out);
    prep_w_kernel<<<dim3(11264), blk, 0, stream>>>(W1, W2, W3, W4, b4,
                                                   W1q, W2q, W3q, W4q, b4p);

    // all GEMMs persistent: grid 256 = 1 block/CU, 512 threads
    // layer 1: K=256 -> NI=4 K-64 tiles, TPB=4, gx=4
    gemmR_kernel<0, 4, 4><<<dim3(256), blk8, 0, stream>>>(xq, W1q, b1, hA, nullptr, nullptr, H, D_ID, 4, invS1);
    // layers 2,3: K=1024 -> NI=16, TPB=4, gx=4
    gemmR_kernel<0, 16, 4><<<dim3(256), blk8, 0, stream>>>(hA, W2q, b2, hB, nullptr, nullptr, H, H, 4, invS23);
    gemmR_kernel<0, 16, 4><<<dim3(256), blk8, 0, stream>>>(hB, W3q, b3, hA, nullptr, nullptr, H, H, 4, invS23);
    // layer 4: N=512 (gx=2), NI=16, TPB=2, fused coupling epilogue
    gemmR_kernel<2, 16, 2><<<dim3(256), blk8, 0, stream>>>(hA, W4q, b4p, out, x, part, NP, H, 2, invS23);

    lad_reduce_kernel<<<dim3(B / 256), blk, 0, stream>>>(part, lad);
}

// Round 16
// 325.623 us; speedup vs baseline: 1.9248x; 1.0312x over previous
//
#include <hip/hip_runtime.h>
#include <hip/hip_bf16.h>
#include <cstdint>
#include <cstddef>

typedef __attribute__((ext_vector_type(4))) int   i32x4;
typedef __attribute__((ext_vector_type(4))) float f32x4;

#define DEVI static __device__ __forceinline__

DEVI void gload_lds16(const void* g, void* l) {
    __builtin_amdgcn_global_load_lds((const __attribute__((address_space(1))) void*)g,
                                     (__attribute__((address_space(3))) void*)l, 16, 0, 0);
}

#define BARR() __builtin_amdgcn_s_barrier()
#define LGKM0() do { asm volatile("s_waitcnt lgkmcnt(0)" ::: "memory"); \
                     __builtin_amdgcn_sched_barrier(0); } while (0)
#define SCHED0() __builtin_amdgcn_sched_barrier(0)
#define VMW(n) asm volatile("s_waitcnt vmcnt(" #n ")" ::: "memory")
#define SP(x) __builtin_amdgcn_s_setprio(x)

DEVI int q8(float v, float s) {
    int q = __float2int_rn(v * s);
    return q < -127 ? -127 : (q > 127 ? 127 : q);
}

// ---------------------------------------------------------------------------
// Prep: quantize x identity half AND write the output identity half.
// ---------------------------------------------------------------------------
__global__ __launch_bounds__(256)
void prep_x_kernel(const float* __restrict__ x, char* __restrict__ xq,
                   float* __restrict__ out) {
    int g = blockIdx.x * 256 + threadIdx.x;     // over B*32
    int row = g >> 5, c8 = (g & 31) * 8;
    const float4 v0 = *(const float4*)(x + (size_t)row * 512 + c8);
    const float4 v1 = *(const float4*)(x + (size_t)row * 512 + c8 + 4);
    *(float4*)(out + (size_t)row * 512 + c8)     = v0;   // identity copy
    *(float4*)(out + (size_t)row * 512 + c8 + 4) = v1;
    unsigned p0 = (q8(v0.x,20.f)&255) | ((q8(v0.y,20.f)&255)<<8) |
                  ((q8(v0.z,20.f)&255)<<16) | ((unsigned)(q8(v0.w,20.f)&255)<<24);
    unsigned p1 = (q8(v1.x,20.f)&255) | ((q8(v1.y,20.f)&255)<<8) |
                  ((q8(v1.z,20.f)&255)<<16) | ((unsigned)(q8(v1.w,20.f)&255)<<24);
    *(int2*)(xq + (size_t)row * 256 + c8) = make_int2((int)p0, (int)p1);
}

// ---------------------------------------------------------------------------
// Merged weight prep: transpose+quant W1,W2,W3; permuted transpose+quant W4.
// ---------------------------------------------------------------------------
__global__ __launch_bounds__(256)
void prep_w_kernel(const float* __restrict__ W1, const float* __restrict__ W2,
                   const float* __restrict__ W3, const float* __restrict__ W4,
                   const float* __restrict__ b4, char* __restrict__ W1q,
                   char* __restrict__ W2q, char* __restrict__ W3q,
                   char* __restrict__ W4q, float* __restrict__ b4p) {
    int idx = blockIdx.x * 256 + threadIdx.x;
    if (idx < 262144) {                         // W1: N=1024, K=256
        int n = idx >> 8, k = idx & 255;
        W1q[idx] = (char)q8(W1[(size_t)k * 1024 + n], 2032.f);
    } else if (idx < 262144 + 1048576) {        // W2: N=K=1024
        int j = idx - 262144;
        int n = j >> 10, k = j & 1023;
        W2q[j] = (char)q8(W2[(size_t)k * 1024 + n], 4064.f);
    } else if (idx < 262144 + 2097152) {        // W3
        int j = idx - 262144 - 1048576;
        int n = j >> 10, k = j & 1023;
        W3q[j] = (char)q8(W3[(size_t)k * 1024 + n], 4064.f);
    } else {                                    // W4 permuted: vt in [0,512)
        int j = idx - 262144 - 2097152;
        int vt = j >> 10, k = j & 1023;
        int bn = vt >> 8, v = vt & 255;
        int v16 = v >> 4, c = v & 15;
        int tcol = bn * 128 + (v16 >> 1) * 16 + c;
        int col = (v16 & 1) ? 256 + tcol : tcol;
        W4q[j] = (char)q8(W4[(size_t)k * 512 + col], 4064.f);
        if (k == 0) b4p[vt] = b4[col];
    }
}

// ===========================================================================
// Kernel A (gemmQ): BK=128, 2 barriers/K-tile, 2-tile prologue — best for
// SHORT K-streams (L1: K=256; L4: N=512/TPB=2).  [R13, passing, 323us total]
// ===========================================================================
#define QRDS(p) do { \
    const char* _a = lds + (p) * 65536; \
    const char* _bb = _a + 32768; \
    _Pragma("unroll") \
    for (int mt = 0; mt < 8; ++mt) aF[mt][0] = *(const i32x4*)(_a + aRow + mt * 2048 + ck0); \
    _Pragma("unroll") \
    for (int nt = 0; nt < 4; ++nt) bF[nt][0] = *(const i32x4*)(_bb + bRow + nt * 2048 + ck0); \
    _Pragma("unroll") \
    for (int mt = 0; mt < 8; ++mt) aF[mt][1] = *(const i32x4*)(_a + aRow + mt * 2048 + ck1); \
    _Pragma("unroll") \
    for (int nt = 0; nt < 4; ++nt) bF[nt][1] = *(const i32x4*)(_bb + bRow + nt * 2048 + ck1); \
} while (0)

#define QMMH(S) do { \
    SP(1); \
    _Pragma("unroll") \
    for (int mt = 0; mt < 8; ++mt) \
        _Pragma("unroll") \
        for (int nt = 0; nt < 4; ++nt) \
            acc[mt][nt] = __builtin_amdgcn_mfma_i32_16x16x64_i8(bF[nt][S], aF[mt][S], acc[mt][nt], 0, 0, 0); \
    SP(0); \
} while (0)

template<int MODE, int NI2, int TPB>
__global__ __launch_bounds__(512)
void gemmQ_kernel(const char* __restrict__ A, const char* __restrict__ Bt,
                  const float* __restrict__ bias, void* __restrict__ Cp,
                  const float* __restrict__ x, float* __restrict__ part,
                  int N, int K, int gx, float invS) {
    constexpr int GT = NI2 * TPB;
    __shared__ __align__(16) char lds[131072]; // 2 x (A 32KB + B 32KB)

    const int tid = threadIdx.x;
    const int bid = blockIdx.x;
    const int xcd = bid & 7, bidx = bid >> 3;
    const int bn = bidx % gx;
    const int mgrp = bidx / gx;
    const int colBase = bn * 256;
    const int l  = tid & 63;
    const int w  = tid >> 6;
    const int wm = w >> 2, wn = w & 3;
    const int lr = l & 15, lq = l >> 4;
    const int gsw = (lr >> 1) & 7;

    const int aRow = (wm * 128 + lr) * 128;
    const int bRow = (wn * 64 + lr) * 128;
    const int ck0 = ((lq ^ gsw) & 7) * 16;
    const int ck1 = (((4 | lq) ^ gsw) & 7) * 16;

    auto rowBaseOf = [&](int tt) { return (xcd * 32 + mgrp * TPB + tt) * 256; };

    auto STAGE = [&](int gd) {
        const int gs = gd < GT ? gd : GT - 1;
        const int kb = (gs & (NI2 - 1)) * 128;
        const int arb = rowBaseOf(gs / NI2);
        char* da = lds + (gd & 1) * 65536;
#pragma unroll
        for (int u = 0; u < 4; ++u) {
            int row = u * 64 + (tid >> 3);
            int c = (tid & 7) ^ ((row >> 1) & 7);
            gload_lds16(A + (size_t)(arb + row) * K + kb + c * 16, da + u * 8192 + tid * 16);
        }
        char* db = lds + (gd & 1) * 65536 + 32768;
#pragma unroll
        for (int u = 0; u < 4; ++u) {
            int row = u * 64 + (tid >> 3);
            int c = (tid & 7) ^ ((row >> 1) & 7);
            gload_lds16(Bt + (size_t)(colBase + row) * K + kb + c * 16, db + u * 8192 + tid * 16);
        }
    };

    i32x4 acc[8][4];
    const i32x4 zero = {0, 0, 0, 0};
#pragma unroll
    for (int m = 0; m < 8; ++m)
#pragma unroll
        for (int n = 0; n < 4; ++n) acc[m][n] = zero;
    i32x4 aF[8][2], bF[4][2];

    auto epi = [&](int tt) {
        float4 bv[4];
#pragma unroll
        for (int n = 0; n < 4; ++n)
            bv[n] = *(const float4*)(bias + colBase + wn * 64 + n * 16 + lq * 4);
        const int rowBase = rowBaseOf(tt);
        const int row0 = rowBase + wm * 128;
        if (MODE == 0) {
            char* C = (char*)Cp;
#pragma unroll
            for (int m = 0; m < 8; ++m) {
                const int row = row0 + m * 16 + lr;
#pragma unroll
                for (int n = 0; n < 4; ++n) {
                    unsigned pack = 0;
#pragma unroll
                    for (int r = 0; r < 4; ++r) {
                        float v = (float)acc[m][n][r] * invS + ((const float*)&bv[n])[r];
                        v = fmaxf(v, 0.f);
                        int q = (int)(fminf(v, 7.9f) * 16.f + 0.5f);
                        pack |= (unsigned)q << (8 * r);
                    }
                    *(int*)(C + (size_t)row * N + colBase + wn * 64 + n * 16 + lq * 4) = (int)pack;
                }
            }
        } else {
            const int B = 65536;
            float* out = (float*)Cp;
#pragma unroll
            for (int m = 0; m < 8; ++m) {
                const int row = row0 + m * 16 + lr;
                float lsum = 0.f;
#pragma unroll
                for (int p = 0; p < 2; ++p) {
                    const int tcol = bn * 128 + wn * 32 + p * 16 + lq * 4;
                    const float4 xt = *(const float4*)(x + (size_t)row * 512 + 256 + tcol);
                    float4 ov;
#pragma unroll
                    for (int r = 0; r < 4; ++r) {
                        float sh = (float)acc[m][2 * p][r]     * invS + ((const float*)&bv[2 * p])[r];
                        float u  = (float)acc[m][2 * p + 1][r] * invS + ((const float*)&bv[2 * p + 1])[r];
                        float s  = 1.f / (1.f + __expf(-(u + 2.f))) + 0.001f;
                        ((float*)&ov)[r] = ((const float*)&xt)[r] * s + sh;
                        lsum += __logf(s);
                    }
                    *(float4*)(out + (size_t)row * 512 + 256 + tcol) = ov;
                }
                lsum += __shfl_xor(lsum, 16);
                lsum += __shfl_xor(lsum, 32);
                if (lq == 0) part[(size_t)(bn * 4 + wn) * B + row] = lsum;
            }
        }
#pragma unroll
        for (int m = 0; m < 8; ++m)
#pragma unroll
            for (int n = 0; n < 4; ++n) acc[m][n] = zero;
    };

    STAGE(0); STAGE(1);
    VMW(0);
    BARR();

#pragma unroll 1
    for (int t = 0; t < GT; ++t) {
        const int p = t & 1;
        QRDS(p);
        QMMH(0);
        LGKM0();
        BARR();
        SCHED0();
        STAGE(t + 2);
        QMMH(1);
        VMW(8);
        SCHED0();
        BARR();
        if (((t + 1) & (NI2 - 1)) == 0) epi((t + 1) / NI2 - 1);
    }
}

// ===========================================================================
// Kernel B (gemmR): BK=64, reg-pipelined, 1 barrier/phase — best for LONG
// K-streams (L2/L3: K=1024, TPB=4).  [R15, passing, 89.2us per H-GEMM]
// ===========================================================================
#define RD_A(DST, g) do { \
    const char* _b = lds + ((g) & 3) * 32768; \
    _Pragma("unroll") \
    for (int m = 0; m < 8; ++m) DST[m] = *(const i32x4*)(_b + aOff + m * 1024); \
} while (0)

#define RD_B(DST, g, J0) do { \
    const char* _b = lds + ((g) & 3) * 32768 + 16384; \
    DST[0] = *(const i32x4*)(_b + bOff + (J0) * 1024); \
    DST[1] = *(const i32x4*)(_b + bOff + (J0 + 1) * 1024); \
} while (0)

#define MM2(BSET, ASET, J0) do { \
    _Pragma("unroll") \
    for (int m = 0; m < 8; ++m) { \
        acc[m][J0]     = __builtin_amdgcn_mfma_i32_16x16x64_i8(BSET[0], ASET[m], acc[m][J0], 0, 0, 0); \
        acc[m][J0 + 1] = __builtin_amdgcn_mfma_i32_16x16x64_i8(BSET[1], ASET[m], acc[m][J0 + 1], 0, 0, 0); \
    } \
} while (0)

#define PHASE0(ASET, t) do { \
    RD_B(b1, (t), 2); \
    STAGE_A((t) + 3); \
    SCHED0(); \
    SP(1); MM2(b0, ASET, 0); SP(0); \
    LGKM0(); BARR(); \
} while (0)

#define PHASE1(ASET, ANXT, t, W0) do { \
    if (W0) { VMW(0); } else { VMW(6); } \
    RD_A(ANXT, (t) + 1); \
    RD_B(b0, (t) + 1, 0); \
    STAGE_B((t) + 3); \
    SCHED0(); \
    SP(1); MM2(b1, ASET, 2); SP(0); \
    LGKM0(); BARR(); \
} while (0)

template<int MODE, int NI, int TPB>
__global__ __launch_bounds__(512)
void gemmR_kernel(const char* __restrict__ A, const char* __restrict__ Bt,
                  const float* __restrict__ bias, void* __restrict__ Cp,
                  const float* __restrict__ x, float* __restrict__ part,
                  int N, int K, int gx, float invS) {
    constexpr int GT = NI * TPB;
    __shared__ __align__(16) char lds[131072]; // 4 x (A 16KB + B 16KB)

    const int tid = threadIdx.x;
    const int bid = blockIdx.x;
    const int xcd = bid & 7, bidx = bid >> 3;
    const int bn = bidx % gx;
    const int mgrp = bidx / gx;
    const int colBase = bn * 256;
    const int l  = tid & 63;
    const int w  = tid >> 6;
    const int wm = w >> 2, wn = w & 3;
    const int lr = l & 15, lq = l >> 4;
    const int qa = lq ^ ((lr >> 1) & 3);

    const int aOff = (wm * 128 + lr) * 64 + qa * 16;
    const int bOff = (wn * 64 + lr) * 64 + qa * 16;

    const int sar = tid >> 2;
    const int ca = (((tid & 3) ^ ((tid >> 3) & 3))) * 16;

    auto rowBaseOf = [&](int tt) { return (xcd * 32 + mgrp * TPB + tt) * 256; };

    auto STAGE_A = [&](int gd) {
        const int gs = gd < GT ? gd : GT - 1;
        char* dst = lds + (gd & 3) * 32768 + tid * 16;
        const char* src = A + (size_t)(rowBaseOf(gs / NI) + sar) * K
                            + (gs & (NI - 1)) * 64 + ca;
#pragma unroll
        for (int u = 0; u < 2; ++u)
            gload_lds16(src + (size_t)u * 128 * K, dst + u * 8192);
    };
    auto STAGE_B = [&](int gd) {
        const int gs = gd < GT ? gd : GT - 1;
        char* dst = lds + (gd & 3) * 32768 + 16384 + tid * 16;
        const char* src = Bt + (size_t)(colBase + sar) * K
                             + (gs & (NI - 1)) * 64 + ca;
#pragma unroll
        for (int u = 0; u < 2; ++u)
            gload_lds16(src + (size_t)u * 128 * K, dst + u * 8192);
    };

    i32x4 acc[8][4];
    const i32x4 zero = {0, 0, 0, 0};
#pragma unroll
    for (int m = 0; m < 8; ++m)
#pragma unroll
        for (int n = 0; n < 4; ++n) acc[m][n] = zero;
    i32x4 afX[8], afY[8], b0[2], b1[2];

    auto epi = [&](int tt) {
        float4 bv[4];
#pragma unroll
        for (int n = 0; n < 4; ++n)
            bv[n] = *(const float4*)(bias + colBase + wn * 64 + n * 16 + lq * 4);
        const int rowBase = rowBaseOf(tt);
        const int row0 = rowBase + wm * 128;
        if (MODE == 0) {
            char* C = (char*)Cp;
#pragma unroll
            for (int m = 0; m < 8; ++m) {
                const int row = row0 + m * 16 + lr;
#pragma unroll
                for (int n = 0; n < 4; ++n) {
                    unsigned pack = 0;
#pragma unroll
                    for (int r = 0; r < 4; ++r) {
                        float v = (float)acc[m][n][r] * invS + ((const float*)&bv[n])[r];
                        v = fmaxf(v, 0.f);
                        int q = (int)(fminf(v, 7.9f) * 16.f + 0.5f);
                        pack |= (unsigned)q << (8 * r);
                    }
                    *(int*)(C + (size_t)row * N + colBase + wn * 64 + n * 16 + lq * 4) = (int)pack;
                }
            }
        } else {
            const int B = 65536;
            float* out = (float*)Cp;
#pragma unroll
            for (int m = 0; m < 8; ++m) {
                const int row = row0 + m * 16 + lr;
                float lsum = 0.f;
#pragma unroll
                for (int p = 0; p < 2; ++p) {
                    const int tcol = bn * 128 + wn * 32 + p * 16 + lq * 4;
                    const float4 xt = *(const float4*)(x + (size_t)row * 512 + 256 + tcol);
                    float4 ov;
#pragma unroll
                    for (int r = 0; r < 4; ++r) {
                        float sh = (float)acc[m][2 * p][r]     * invS + ((const float*)&bv[2 * p])[r];
                        float u  = (float)acc[m][2 * p + 1][r] * invS + ((const float*)&bv[2 * p + 1])[r];
                        float s  = 1.f / (1.f + __expf(-(u + 2.f))) + 0.001f;
                        ((float*)&ov)[r] = ((const float*)&xt)[r] * s + sh;
                        lsum += __logf(s);
                    }
                    *(float4*)(out + (size_t)row * 512 + 256 + tcol) = ov;
                }
                lsum += __shfl_xor(lsum, 16);
                lsum += __shfl_xor(lsum, 32);
                if (lq == 0) part[(size_t)(bn * 4 + wn) * B + row] = lsum;
            }
        }
#pragma unroll
        for (int m = 0; m < 8; ++m)
#pragma unroll
            for (int n = 0; n < 4; ++n) acc[m][n] = zero;
    };

    STAGE_A(0); STAGE_B(0); STAGE_A(1); STAGE_B(1); STAGE_A(2); STAGE_B(2);
    VMW(0);
    BARR();
    RD_A(afX, 0); RD_B(b0, 0, 0);
    LGKM0();

#pragma unroll 1
    for (int g = 0; g < GT / 2; ++g) {
        const int ta = 2 * g, tb = 2 * g + 1;
        const bool w0 = (ta > 0) && ((ta & (NI - 1)) == 0);
        PHASE0(afX, ta);
        PHASE1(afX, afY, ta, w0);
        PHASE0(afY, tb);
        PHASE1(afY, afX, tb, false);
        if (((tb + 1) & (NI - 1)) == 0) epi((tb + 1) / NI - 1);
    }
}

__global__ __launch_bounds__(256)
void lad_reduce_kernel(const float* __restrict__ part, float* __restrict__ lad) {
    const int B = 65536;
    int rIdx = blockIdx.x * 256 + threadIdx.x;
    float s = 0.f;
#pragma unroll
    for (int j = 0; j < 8; ++j) s += part[(size_t)j * B + rIdx];
    lad[rIdx] = s;
}

// ---------------------------------------------------------------------------
extern "C" void kernel_launch(void* const* d_in, const int* in_sizes, int n_in,
                              void* d_out, int out_size, void* d_ws, size_t ws_size,
                              hipStream_t stream) {
    const int B = 65536, D_ID = 256, H = 1024, NP = 512;

    const float* x  = (const float*)d_in[0];
    const float* W1 = (const float*)d_in[1];
    const float* b1 = (const float*)d_in[2];
    const float* W2 = (const float*)d_in[3];
    const float* b2 = (const float*)d_in[4];
    const float* W3 = (const float*)d_in[5];
    const float* b3 = (const float*)d_in[6];
    const float* W4 = (const float*)d_in[7];
    const float* b4 = (const float*)d_in[8];

    float* out = (float*)d_out;
    float* lad = out + (size_t)B * 512;

    const float invS1  = 1.f / (20.f * 2032.f);
    const float invS23 = 1.f / (16.f * 4064.f);

    char* ws = (char*)d_ws;
    const size_t hbytes = (size_t)B * H;                       // 64 MiB (i8)
    char*  hA   = ws;
    char*  hB   = ws + hbytes;
    char*  xq   = ws + hbytes;                                 // alias hB (dead before L2)
    float* part = (float*)(ws + hbytes);                       // alias hB (dead after L3)
    char*  W1q  = ws + 2 * hbytes;
    char*  W2q  = W1q + (size_t)H * D_ID;
    char*  W3q  = W2q + (size_t)H * H;
    char*  W4q  = W3q + (size_t)H * H;
    float* b4p  = (float*)(W4q + (size_t)NP * H);

    dim3 blk(256), blk8(512);
    prep_x_kernel<<<dim3(B * 32 / 256), blk, 0, stream>>>(x, xq, out);
    prep_w_kernel<<<dim3(11264), blk, 0, stream>>>(W1, W2, W3, W4, b4,
                                                   W1q, W2q, W3q, W4q, b4p);

    // persistent GEMMs, grid 256 = 1 block/CU; structure routed by shape:
    // short K-stream layers -> gemmQ (BK=128); long -> gemmR (BK=64).
    gemmQ_kernel<0, 2, 4><<<dim3(256), blk8, 0, stream>>>(xq, W1q, b1, hA, nullptr, nullptr, H, D_ID, 4, invS1);
    gemmR_kernel<0, 16, 4><<<dim3(256), blk8, 0, stream>>>(hA, W2q, b2, hB, nullptr, nullptr, H, H, 4, invS23);
    gemmR_kernel<0, 16, 4><<<dim3(256), blk8, 0, stream>>>(hB, W3q, b3, hA, nullptr, nullptr, H, H, 4, invS23);
    gemmQ_kernel<2, 8, 2><<<dim3(256), blk8, 0, stream>>>(hA, W4q, b4p, out, x, part, NP, H, 2, invS23);

    lad_reduce_kernel<<<dim3(B / 256), blk, 0, stream>>>(part, lad);
}